// Round 12
// baseline (666.729 us; speedup 1.0000x reference)
//
#include <hip/hip_runtime.h>
#include <cstdint>

#define B_  2
#define S_  1024
#define H_  1024
#define NH_ 16
#define DH_ 64
#define F_  4096
#define L_  4
#define M_  (B_*S_)        // 2048 rows in all GEMMs

typedef __bf16 bf16;
typedef __bf16 bf16x8 __attribute__((ext_vector_type(8)));
typedef __bf16 bf16x4 __attribute__((ext_vector_type(4)));
typedef __bf16 bf16x2 __attribute__((ext_vector_type(2)));
typedef float  f32x4  __attribute__((ext_vector_type(4)));

// ---------------- async global->LDS (16B per lane), CK-style addrspace cast ----
__device__ __forceinline__ void async_ld16(void* lds, const void* g) {
  auto* lp = reinterpret_cast<__attribute__((address_space(3))) unsigned int*>(
      reinterpret_cast<uintptr_t>(lds));
  const auto* gp = reinterpret_cast<const __attribute__((address_space(1))) unsigned int*>(
      reinterpret_cast<uintptr_t>(g));
  __builtin_amdgcn_global_load_lds(gp, lp, 16, 0, 0);
}

__device__ __forceinline__ float gelu_tanh(float x) {
  float u = 0.7978845608028654f * (x + 0.044715f * x * x * x);
  u = fminf(fmaxf(u, -15.f), 15.f);
  float e = __builtin_amdgcn_exp2f(u * 2.8853900817779268f); // exp(2u)
  return 0.5f * x * (1.f + (e - 1.f) / (e + 1.f));
}

// ---------------- prep: mask -> bf16 log2 adder + x init (weights untouched) ---
__global__ __launch_bounds__(256) void prep_kernel(
    const float4* __restrict__ mask, bf16x4* __restrict__ madd,
    const float4* __restrict__ x, float4* __restrict__ xf,
    bf16x4* __restrict__ xb) {
  const int blk = blockIdx.x;
  if (blk < 2048) {
    const int i = blk * 256 + (int)threadIdx.x;
    const float c2 = -10000.f * 1.44269504088896f;
    float4 v = mask[i];
    bf16x4 o;
    o[0] = (bf16)((1.f - v.x) * c2);
    o[1] = (bf16)((1.f - v.y) * c2);
    o[2] = (bf16)((1.f - v.z) * c2);
    o[3] = (bf16)((1.f - v.w) * c2);
    madd[i] = o;
  } else {
    const int i = (blk - 2048) * 256 + (int)threadIdx.x;
    float4 v = x[i];
    xf[i] = v;
    bf16x4 b;
    b[0] = (bf16)v.x; b[1] = (bf16)v.y; b[2] = (bf16)v.z; b[3] = (bf16)v.w;
    xb[i] = b;
  }
}

// ---------------- GEMM core v2: A bf16 (async LDS), B = fp32 W[K][N] direct ----
// Per K-step: wave w owns k-chunk w*8..w*8+7. 8 wave-wide float2 row loads give
// lane l the k-contiguous 8-run for columns n0+2l / n0+2l+1 -> cvt -> two
// ds_write_b128 into Bs[n][k] (pad-40 rows). T14 split: loads issue BEFORE the
// MFMAs, cvt+write after (latency hides under compute). Frag reads unchanged.
__device__ __forceinline__ void gemm_core(
    const bf16* __restrict__ A, const float* __restrict__ W, int ldA, int N,
    int kLen, int m0, int n0, bf16* As, bf16* Bs, f32x4 (&acc)[4][4]) {
  const int tid = (int)threadIdx.x;
  const int w = tid >> 6, l = tid & 63;
  const int lr = l & 15, lg = l >> 4;
  const int wm = w >> 1, wn = w & 1;
  const int srow = l >> 2;
  const int scol = (l & 3) * 8;

  const bf16* ag = A + (size_t)(m0 + w * 32 + srow) * ldA + scol;
  const int aoff = (w * 32) * 32;
  const float* wg = W + (size_t)(w * 8) * N + n0 + 2 * l;

  auto stageA = [&](int buf, int kk) {
    bf16* ad = As + buf * 4096 + aoff;
    async_ld16(ad,           ag + kk);
    async_ld16(ad + 16 * 32, ag + kk + (size_t)16 * ldA);
  };
  float2 bl[8];
  auto loadB = [&](int kk) {
    const float* p = wg + (size_t)kk * N;
    #pragma unroll
    for (int i = 0; i < 8; ++i) bl[i] = *(const float2*)(p + (size_t)i * N);
  };
  auto writeB = [&](int buf) {
    bf16x8 v0, v1;
    #pragma unroll
    for (int i = 0; i < 8; ++i) { v0[i] = (bf16)bl[i].x; v1[i] = (bf16)bl[i].y; }
    bf16* bd = Bs + buf * 5120;                  // 128 rows * 40
    *(bf16x8*)(bd + (2 * l) * 40 + w * 8)     = v0;
    *(bf16x8*)(bd + (2 * l + 1) * 40 + w * 8) = v1;
  };

  stageA(0, 0);
  loadB(0);
  writeB(0);
  __syncthreads();
  int cur = 0;
  for (int k0 = 0; k0 < kLen; k0 += 32) {
    const bool more = (k0 + 32 < kLen);
    if (more) { stageA(cur ^ 1, k0 + 32); loadB(k0 + 32); }
    const bf16* Ab = As + cur * 4096;
    const bf16* Bb = Bs + cur * 5120;
    bf16x8 af[4], bv[4];
    #pragma unroll
    for (int i = 0; i < 4; ++i)
      af[i] = *(const bf16x8*)(Ab + (wm * 64 + i * 16 + lr) * 32 + lg * 8);
    #pragma unroll
    for (int i = 0; i < 4; ++i)
      bv[i] = *(const bf16x8*)(Bb + (wn * 64 + i * 16 + lr) * 40 + lg * 8);
    #pragma unroll
    for (int i = 0; i < 4; ++i)
      #pragma unroll
      for (int j = 0; j < 4; ++j)
        acc[i][j] = __builtin_amdgcn_mfma_f32_16x16x32_bf16(af[i], bv[j], acc[i][j], 0, 0, 0);
    if (more) writeB(cur ^ 1);        // vmcnt-wait lands AFTER the 16 MFMA
    __syncthreads();
    cur ^= 1;
  }
}

// MODE 1: out_bf16 = gelu(acc+bias) | MODE 3: bf16 partial -> outb[z*M*N + idx]
// W = fp32 [K][N] (row stride N). Split-K: A cols + W rows offset by z*kSlice.
template <int MODE>
__global__ __launch_bounds__(256) void gemm128_kernel(
    const bf16* __restrict__ A, const float* __restrict__ W,
    const float* __restrict__ bias, bf16* __restrict__ outb,
    int N, int K, int kSlice) {
  __shared__ __align__(16) bf16 As[2 * 128 * 32];   // 16KB
  __shared__ __align__(16) bf16 Bs[2 * 128 * 40];   // 20KB
  const int m0 = blockIdx.y * 128, n0 = blockIdx.x * 128;
  const int z = blockIdx.z;
  const f32x4 z4 = {0.f, 0.f, 0.f, 0.f};
  f32x4 acc[4][4];
  #pragma unroll
  for (int i = 0; i < 4; ++i)
    #pragma unroll
    for (int j = 0; j < 4; ++j) acc[i][j] = z4;

  gemm_core(A + (size_t)z * kSlice, W + (size_t)z * kSlice * N, K, N, kSlice,
            m0, n0, As, Bs, acc);

  const int tid = (int)threadIdx.x;
  const int w = tid >> 6, l = tid & 63;
  const int lr = l & 15, lg = l >> 4;
  const int wm = w >> 1, wn = w & 1;
  const size_t pbase = (MODE == 3) ? (size_t)z * M_ * (size_t)N : 0;
  #pragma unroll
  for (int i = 0; i < 4; ++i) {
    const int row0 = m0 + wm * 64 + i * 16 + lg * 4;
    #pragma unroll
    for (int j = 0; j < 4; ++j) {
      const int col = n0 + wn * 64 + j * 16 + lr;
      const float bvx = (MODE == 3) ? 0.f : bias[col];
      #pragma unroll
      for (int r = 0; r < 4; ++r) {
        const size_t idx = (size_t)(row0 + r) * N + col;
        float v = acc[i][j][r] + bvx;
        if (MODE == 3) {
          outb[pbase + idx] = (bf16)v;
        } else {
          outb[idx] = (bf16)gelu_tanh(v);
        }
      }
    }
  }
}

// ---------------- split-K reduce (bf16 partials, z=4) + bias + ReZero ---------
__global__ __launch_bounds__(256) void reduce_residual(
    const bf16x4* __restrict__ part, const float* __restrict__ bias,
    const float* __restrict__ alphap, float4* __restrict__ xf,
    bf16x4* __restrict__ xb) {
  const int i = blockIdx.x * 256 + (int)threadIdx.x;   // over M_*H_/4
  const int nper = M_ * H_ / 4;
  float s[4] = {0.f, 0.f, 0.f, 0.f};
  #pragma unroll
  for (int zz = 0; zz < 4; ++zz) {
    const bf16x4 p = part[i + (size_t)zz * nper];
    #pragma unroll
    for (int k = 0; k < 4; ++k) s[k] += (float)p[k];
  }
  const int col = (i * 4) & (H_ - 1);
  const float4 b4 = *(const float4*)(bias + col);
  const float a = *alphap;
  float4 xv = xf[i];
  xv.x += a * (s[0] + b4.x);
  xv.y += a * (s[1] + b4.y);
  xv.z += a * (s[2] + b4.z);
  xv.w += a * (s[3] + b4.w);
  xf[i] = xv;
  bf16x4 bb;
  bb[0] = (bf16)xv.x; bb[1] = (bf16)xv.y; bb[2] = (bf16)xv.z; bb[3] = (bf16)xv.w;
  xb[i] = bb;
}

// ---------------- QKV GEMM, BN=64, fp32 W direct: grid (48, 16) ---------------
// n0 in [0,3072) selects wq/wk/wv (each [1024][1024] fp32, row stride H).
// Wave w owns k-chunk w*8..+7; lane l covers column n0+l (8 fp32 loads, 4B
// each, wave-contiguous 256B) -> one ds_write_b128 per thread per K-step.
__global__ __launch_bounds__(256) void gemm_qkv64(
    const bf16* __restrict__ A, const float* __restrict__ wq,
    const float* __restrict__ wk, const float* __restrict__ wv,
    const float* __restrict__ bq, const float* __restrict__ bk,
    const float* __restrict__ bvv,
    bf16* __restrict__ qo, bf16* __restrict__ ko, bf16* __restrict__ vt) {
  __shared__ __align__(16) bf16 As[2 * 128 * 32];   // 16KB
  __shared__ __align__(16) bf16 Bs[2 * 64 * 40];    //  10KB
  const int tid = (int)threadIdx.x;
  const int w = tid >> 6, l = tid & 63;
  const int lr = l & 15, lg = l >> 4;
  const int wm = w >> 1, wn = w & 1;
  const int srow = l >> 2, scol = (l & 3) * 8;
  const int m0 = blockIdx.y * 128, n0 = blockIdx.x * 64;

  const float* Wsel = (n0 < 1024) ? wq : (n0 < 2048) ? wk : wv;
  const int nl = n0 & 1023;

  const bf16* ag = A + (size_t)(m0 + w * 32 + srow) * H_ + scol;
  const int aoff = (w * 32) * 32;
  const float* wg = Wsel + (size_t)(w * 8) * H_ + nl + l;

  auto stageA = [&](int buf, int kk) {
    bf16* ad = As + buf * 4096 + aoff;
    async_ld16(ad,           ag + kk);
    async_ld16(ad + 16 * 32, ag + kk + (size_t)16 * H_);
  };
  float bl[8];
  auto loadB = [&](int kk) {
    const float* p = wg + (size_t)kk * H_;
    #pragma unroll
    for (int i = 0; i < 8; ++i) bl[i] = p[(size_t)i * H_];
  };
  auto writeB = [&](int buf) {
    bf16x8 v0;
    #pragma unroll
    for (int i = 0; i < 8; ++i) v0[i] = (bf16)bl[i];
    *(bf16x8*)(Bs + buf * 2560 + l * 40 + w * 8) = v0;
  };

  const f32x4 z4 = {0.f, 0.f, 0.f, 0.f};
  f32x4 acc[4][2];
  #pragma unroll
  for (int i = 0; i < 4; ++i)
    #pragma unroll
    for (int j = 0; j < 2; ++j) acc[i][j] = z4;

  stageA(0, 0);
  loadB(0);
  writeB(0);
  __syncthreads();
  int cur = 0;
  for (int k0 = 0; k0 < H_; k0 += 32) {
    const bool more = (k0 + 32 < H_);
    if (more) { stageA(cur ^ 1, k0 + 32); loadB(k0 + 32); }
    const bf16* Ab = As + cur * 4096;
    const bf16* Bb = Bs + cur * 2560;
    bf16x8 af[4], bv[2];
    #pragma unroll
    for (int i = 0; i < 4; ++i)
      af[i] = *(const bf16x8*)(Ab + (wm * 64 + i * 16 + lr) * 32 + lg * 8);
    #pragma unroll
    for (int j = 0; j < 2; ++j)
      bv[j] = *(const bf16x8*)(Bb + (wn * 32 + j * 16 + lr) * 40 + lg * 8);
    #pragma unroll
    for (int i = 0; i < 4; ++i)
      #pragma unroll
      for (int j = 0; j < 2; ++j)
        acc[i][j] = __builtin_amdgcn_mfma_f32_16x16x32_bf16(af[i], bv[j], acc[i][j], 0, 0, 0);
    if (more) writeB(cur ^ 1);
    __syncthreads();
    cur ^= 1;
  }

  if (n0 < 2048) {  // Q or K: direct [B,S,H] store
    bf16* out = (n0 < 1024) ? qo : ko;
    const float* bias = (n0 < 1024) ? bq : bk;
    #pragma unroll
    for (int i = 0; i < 4; ++i) {
      const int row0 = m0 + wm * 64 + i * 16 + lg * 4;
      #pragma unroll
      for (int j = 0; j < 2; ++j) {
        const int col = nl + wn * 32 + j * 16 + lr;
        const float bvx = bias[col];
        #pragma unroll
        for (int r = 0; r < 4; ++r)
          out[(size_t)(row0 + r) * H_ + col] = (bf16)(acc[i][j][r] + bvx);
      }
    }
  } else {          // V: transposed store Vt[((b*NH+h)*DH+d)*S + s]
    const int hh = (n0 >> 6) - 32;
    #pragma unroll
    for (int i = 0; i < 4; ++i) {
      const int row0 = m0 + wm * 64 + i * 16 + lg * 4;
      const int bb = row0 >> 10, ss = row0 & (S_ - 1);
      #pragma unroll
      for (int j = 0; j < 2; ++j) {
        const int dd = wn * 32 + j * 16 + lr;
        const float bvx = bvv[hh * 64 + dd];
        bf16x4 pk;
        #pragma unroll
        for (int r = 0; r < 4; ++r) pk[r] = (bf16)(acc[i][j][r] + bvx);
        *(bf16x4*)(vt + (((size_t)(bb * NH_ + hh) * DH_ + dd) << 10) + ss) = pk;
      }
    }
  }
}

// ---------------- flash attention v7: LDS-staged K/V + mask reg-pipeline ------
__global__ __launch_bounds__(256) void attn_kernel7(
    const bf16* __restrict__ Q, const bf16* __restrict__ Kb,
    const bf16* __restrict__ Vt, const bf16* __restrict__ madd,
    bf16* __restrict__ Ctx) {
  const int tid = (int)threadIdx.x;
  const int w = tid >> 6, l = tid & 63;
  const int lr = l & 15, lg = l >> 4;
  const int r7 = lr & 7;
  const int h = blockIdx.y, b = blockIdx.z;
  const int q0 = blockIdx.x * 64 + w * 16;

  __shared__ __align__(16) bf16 Kt[2][64 * 64];  // [buf][kv][d] swizzled
  __shared__ __align__(16) bf16 Vs[2][64 * 64];  // [buf][d][kv] swizzled
  __shared__ unsigned int Pu[4][16][36];         // per-wave P, u32-packed bf16

  const bf16* qp = Q + ((size_t)(b * S_ + q0 + lr)) * H_ + h * DH_;
  const bf16x8 qa0 = *(const bf16x8*)(qp + lg * 8);
  const bf16x8 qa1 = *(const bf16x8*)(qp + 32 + lg * 8);

  const f32x4 z4 = {0.f, 0.f, 0.f, 0.f};
  f32x4 acc[4];
  #pragma unroll
  for (int dt = 0; dt < 4; ++dt) acc[dt] = z4;
  float mrow = -1e30f, ssum = 0.f;

  const bf16* Kbase = Kb + ((size_t)b * S_) * H_ + h * DH_;
  const bf16* Vbase = Vt + ((size_t)(b * NH_ + h)) * DH_ * S_;
  const bf16* Mb = madd + ((size_t)(b * S_ + q0 + lr)) * S_;

  const float c1 = 0.125f * 1.44269504088896f;   // scale * log2(e)
  const float THR = 10.f;                        // defer-max headroom (base-2)

  const int sub = l >> 3;
  const int cs  = ((l & 7) ^ sub) * 8;
  auto stage = [&](int buf, int kv) {
    #pragma unroll
    for (int j = 0; j < 2; ++j) {
      const int rbase = w * 16 + j * 8;
      async_ld16(&Kt[buf][rbase * 64],
                 Kbase + (size_t)(kv + rbase + sub) * H_ + cs);
      async_ld16(&Vs[buf][rbase * 64],
                 Vbase + (size_t)(rbase + sub) * S_ + kv + cs);
    }
  };

  stage(0, 0);
  bf16x4 mk[4];
  #pragma unroll
  for (int t = 0; t < 4; ++t) mk[t] = *(const bf16x4*)(Mb + t * 16 + lg * 4);
  __syncthreads();                    // vmcnt(0) drain: tile 0 ready
  int cur = 0;
  #pragma unroll 1
  for (int it = 0; it < 16; ++it) {
    const int kv0 = it * 64;
    if (it < 15) stage(cur ^ 1, kv0 + 64);   // async prefetch next K/V tile
    bf16x4 mkn[4];
    if (it < 15) {
      #pragma unroll
      for (int t = 0; t < 4; ++t)
        mkn[t] = *(const bf16x4*)(Mb + kv0 + 64 + t * 16 + lg * 4);
    }
    const bf16* Kc = &Kt[cur][0];
    const bf16* Vc = &Vs[cur][0];
    bf16x8 kf0[4], kf1[4];
    #pragma unroll
    for (int t = 0; t < 4; ++t) {
      kf0[t] = *(const bf16x8*)(Kc + (t * 16 + lr) * 64 + ((lg ^ r7) * 8));
      kf1[t] = *(const bf16x8*)(Kc + (t * 16 + lr) * 64 + (((4 + lg) ^ r7) * 8));
    }
    f32x4 st[4];
    __builtin_amdgcn_s_setprio(1);
    #pragma unroll
    for (int t = 0; t < 4; ++t) {
      f32x4 s = __builtin_amdgcn_mfma_f32_16x16x32_bf16(kf0[t], qa0, z4, 0, 0, 0);
      st[t] = __builtin_amdgcn_mfma_f32_16x16x32_bf16(kf1[t], qa1, s, 0, 0, 0);
    }
    __builtin_amdgcn_s_setprio(0);
    float sv[4][4];
    #pragma unroll
    for (int t = 0; t < 4; ++t)
      #pragma unroll
      for (int r = 0; r < 4; ++r)
        sv[t][r] = st[t][r] * c1 + (float)mk[t][r];
    float nm = sv[0][0];
    #pragma unroll
    for (int t = 0; t < 4; ++t)
      #pragma unroll
      for (int r = 0; r < 4; ++r) nm = fmaxf(nm, sv[t][r]);
    nm = fmaxf(nm, __shfl_xor(nm, 16));
    nm = fmaxf(nm, __shfl_xor(nm, 32));
    if (__any(nm > mrow + THR)) {
      float newm = fmaxf(mrow, nm);
      float f = __builtin_amdgcn_exp2f(mrow - newm);
      mrow = newm;
      ssum *= f;
      #pragma unroll
      for (int dt = 0; dt < 4; ++dt)
        #pragma unroll
        for (int r = 0; r < 4; ++r) acc[dt][r] *= f;
    }
    float p[4][4];
    float ps = 0.f;
    #pragma unroll
    for (int t = 0; t < 4; ++t)
      #pragma unroll
      for (int r = 0; r < 4; ++r) {
        p[t][r] = __builtin_amdgcn_exp2f(sv[t][r] - mrow);
        ps += p[t][r];
      }
    ps += __shfl_xor(ps, 16);
    ps += __shfl_xor(ps, 32);
    ssum += ps;
    #pragma unroll
    for (int t = 0; t < 4; ++t)
      #pragma unroll
      for (int hh = 0; hh < 2; ++hh) {
        union { bf16x2 v; unsigned int u; } pk;
        pk.v[0] = (bf16)p[t][2 * hh];
        pk.v[1] = (bf16)p[t][2 * hh + 1];
        Pu[w][lr][8 * t + 2 * lg + hh] = pk.u;
      }
    const bf16x8 pf0 = *(const bf16x8*)&Pu[w][lr][4 * lg];
    const bf16x8 pf1 = *(const bf16x8*)&Pu[w][lr][16 + 4 * lg];
    __builtin_amdgcn_s_setprio(1);
    #pragma unroll
    for (int dt = 0; dt < 4; ++dt) {
      bf16x8 vb0 = *(const bf16x8*)(Vc + (dt * 16 + lr) * 64 + ((lg ^ r7) * 8));
      acc[dt] = __builtin_amdgcn_mfma_f32_16x16x32_bf16(vb0, pf0, acc[dt], 0, 0, 0);
    }
    #pragma unroll
    for (int dt = 0; dt < 4; ++dt) {
      bf16x8 vb1 = *(const bf16x8*)(Vc + (dt * 16 + lr) * 64 + (((4 + lg) ^ r7) * 8));
      acc[dt] = __builtin_amdgcn_mfma_f32_16x16x32_bf16(vb1, pf1, acc[dt], 0, 0, 0);
    }
    __builtin_amdgcn_s_setprio(0);
    if (it < 15) {
      #pragma unroll
      for (int t = 0; t < 4; ++t) mk[t] = mkn[t];
    }
    __syncthreads();                  // drains prefetch (next tile ready), frees cur
    cur ^= 1;
  }
  const float inv = 1.f / ssum;
  bf16* cp = Ctx + ((size_t)(b * S_ + q0 + lr)) * H_ + h * DH_;
  #pragma unroll
  for (int dt = 0; dt < 4; ++dt) {
    bf16x4 o;
    #pragma unroll
    for (int r = 0; r < 4; ++r) o[r] = (bf16)(acc[dt][r] * inv);
    *(bf16x4*)(cp + dt * 16 + lg * 4) = o;
  }
}

// ---------------- launcher ----------------------------------------------------
extern "C" void kernel_launch(void* const* d_in, const int* in_sizes, int n_in,
                              void* d_out, int out_size, void* d_ws, size_t ws_size,
                              hipStream_t stream) {
  (void)in_sizes; (void)n_in; (void)out_size; (void)ws_size;
  const float* x    = (const float*)d_in[0];
  const float* mask = (const float*)d_in[1];
  const float* wq   = (const float*)d_in[2];
  const float* bq   = (const float*)d_in[3];
  const float* wk   = (const float*)d_in[4];
  const float* bk   = (const float*)d_in[5];
  const float* wv   = (const float*)d_in[6];
  const float* bv   = (const float*)d_in[7];
  const float* wo   = (const float*)d_in[8];
  const float* bo   = (const float*)d_in[9];
  const float* aat  = (const float*)d_in[10];
  const float* wi   = (const float*)d_in[11];
  const float* bi   = (const float*)d_in[12];
  const float* wf   = (const float*)d_in[13];
  const float* bf_  = (const float*)d_in[14];
  const float* afn  = (const float*)d_in[15];

  char* ws = (char*)d_ws;
  size_t o = 0;
  bf16* madd = (bf16*)(ws + o); o += (size_t)B_ * S_ * S_ * 2;      //  4MB
  bf16* xb  = (bf16*)(ws + o); o += (size_t)M_ * H_ * 2;            //  4MB
  bf16* qb  = (bf16*)(ws + o); o += (size_t)M_ * H_ * 2;
  bf16* kbf = (bf16*)(ws + o); o += (size_t)M_ * H_ * 2;
  bf16* vt  = (bf16*)(ws + o); o += (size_t)M_ * H_ * 2;
  bf16* ctx = (bf16*)(ws + o); o += (size_t)M_ * H_ * 2;
  bf16* itm = (bf16*)(ws + o); o += (size_t)M_ * F_ * 2;            // 16MB
  bf16* partb = (bf16*)(ws + o); o += (size_t)4 * M_ * H_ * 2;      // 16MB

  float* xf = (float*)d_out;  // running x lives in d_out (fp32)

  const size_t HH = (size_t)H_ * H_;
  const size_t HF = (size_t)H_ * F_;
  prep_kernel<<<dim3(4096), 256, 0, stream>>>(
      (const float4*)mask, (bf16x4*)madd, (const float4*)x, (float4*)xf,
      (bf16x4*)xb);

  for (int l = 0; l < L_; ++l) {
    gemm_qkv64<<<dim3(48, M_/128), 256, 0, stream>>>(
        xb, wq + (size_t)l * HH, wk + (size_t)l * HH, wv + (size_t)l * HH,
        bq + l * H_, bk + l * H_, bv + l * H_, qb, kbf, vt);
    attn_kernel7<<<dim3(S_/64, NH_, B_), 256, 0, stream>>>(
        qb, kbf, vt, madd, ctx);
    gemm128_kernel<3><<<dim3(H_/128, M_/128, 4), 256, 0, stream>>>(
        ctx, wo + (size_t)l * HH, nullptr, partb, H_, H_, H_ / 4);
    reduce_residual<<<dim3((M_ * H_ / 4) / 256), 256, 0, stream>>>(
        (const bf16x4*)partb, bo + l * H_, aat + l, (float4*)xf, (bf16x4*)xb);
    gemm128_kernel<1><<<dim3(F_/128, M_/128), 256, 0, stream>>>(
        xb, wi + (size_t)l * HF, bi + l * F_, itm, F_, H_, H_);
    gemm128_kernel<3><<<dim3(H_/128, M_/128, 4), 256, 0, stream>>>(
        itm, wf + (size_t)l * HF, nullptr, partb, H_, F_, F_ / 4);
    reduce_residual<<<dim3((M_ * H_ / 4) / 256), 256, 0, stream>>>(
        (const bf16x4*)partb, bf_ + l * H_, afn + l, (float4*)xf, (bf16x4*)xb);
  }
}

// Round 13
// 598.451 us; speedup vs baseline: 1.1141x; 1.1141x over previous
//
#include <hip/hip_runtime.h>
#include <cstdint>

#define B_  2
#define S_  1024
#define H_  1024
#define NH_ 16
#define DH_ 64
#define F_  4096
#define L_  4
#define M_  (B_*S_)        // 2048 rows in all GEMMs

typedef __bf16 bf16;
typedef __bf16 bf16x8 __attribute__((ext_vector_type(8)));
typedef __bf16 bf16x4 __attribute__((ext_vector_type(4)));
typedef __bf16 bf16x2 __attribute__((ext_vector_type(2)));
typedef float  f32x4  __attribute__((ext_vector_type(4)));

// ---------------- async global->LDS (16B per lane), CK-style addrspace cast ----
__device__ __forceinline__ void async_ld16(void* lds, const void* g) {
  auto* lp = reinterpret_cast<__attribute__((address_space(3))) unsigned int*>(
      reinterpret_cast<uintptr_t>(lds));
  const auto* gp = reinterpret_cast<const __attribute__((address_space(1))) unsigned int*>(
      reinterpret_cast<uintptr_t>(g));
  __builtin_amdgcn_global_load_lds(gp, lp, 16, 0, 0);
}

__device__ __forceinline__ float gelu_tanh(float x) {
  float u = 0.7978845608028654f * (x + 0.044715f * x * x * x);
  u = fminf(fmaxf(u, -15.f), 15.f);
  float e = __builtin_amdgcn_exp2f(u * 2.8853900817779268f); // exp(2u)
  return 0.5f * x * (1.f + (e - 1.f) / (e + 1.f));
}

// ---------------- fused prep: weight transpose+cvt (async-staged) + mask/x ----
// Blocks [0,3072): transpose 128k x 128n fp32 tiles via global_load_lds.
// Blocks [3072,5120): mask -> bf16 log2 adder. [5120,7168): x init.
__global__ __launch_bounds__(256) void prep_all(
    const float* __restrict__ wq, const float* __restrict__ wk,
    const float* __restrict__ wv, const float* __restrict__ wo,
    const float* __restrict__ wi, const float* __restrict__ wf,
    bf16* __restrict__ WtQKV, bf16* __restrict__ WtO,
    bf16* __restrict__ WtI, bf16* __restrict__ WtF,
    const float4* __restrict__ mask, bf16x4* __restrict__ madd,
    const float4* __restrict__ x, float4* __restrict__ xf,
    bf16x4* __restrict__ xb) {
  __shared__ __align__(16) float t[128 * 128];   // 64KB, [k][n] linear (async dest)
  const int tid = (int)threadIdx.x;
  int idx = blockIdx.x;
  if (idx >= 3072) {
    idx -= 3072;
    if (idx < 2048) {                            // mask -> log2-domain bf16 adder
      const int i = idx * 256 + tid;
      const float c2 = -10000.f * 1.44269504088896f;
      float4 v = mask[i];
      bf16x4 o;
      o[0] = (bf16)((1.f - v.x) * c2);
      o[1] = (bf16)((1.f - v.y) * c2);
      o[2] = (bf16)((1.f - v.z) * c2);
      o[3] = (bf16)((1.f - v.w) * c2);
      madd[i] = o;
    } else {                                     // x -> xf fp32 + xb bf16
      const int i = (idx - 2048) * 256 + tid;
      float4 v = x[i];
      xf[i] = v;
      bf16x4 b;
      b[0] = (bf16)v.x; b[1] = (bf16)v.y; b[2] = (bf16)v.z; b[3] = (bf16)v.w;
      xb[i] = b;
    }
    return;
  }
  // ---- transpose segment decode (128x128 tiles) ----
  const size_t HH = (size_t)H_ * H_;
  const size_t HF = (size_t)H_ * F_;
  const float* src;
  bf16* dst;
  int N, K, kk0, n0;
  if (idx < 1024) {
    const int mat = idx >> 6;                    // 16 mats: 4 weights x 4 layers
    const int s = mat >> 2, l = mat & 3;
    const int tt = idx & 63;                     // 8 kt x 8 nt
    kk0 = (tt >> 3) * 128; n0 = (tt & 7) * 128;
    N = H_; K = H_;
    src = (s == 0 ? wq : s == 1 ? wk : s == 2 ? wv : wo) + (size_t)l * HH;
    dst = (s < 3) ? (WtQKV + (size_t)l * 3 * HH + (size_t)s * HH)
                  : (WtO + (size_t)l * HH);
  } else if (idx < 2048) {
    const int j = idx - 1024;                    // wi [1024][4096]: 8 kt x 32 nt
    const int l = j >> 8;
    const int tt = j & 255;
    kk0 = (tt >> 5) * 128; n0 = (tt & 31) * 128;
    N = F_; K = H_;
    src = wi + (size_t)l * HF;
    dst = WtI + (size_t)l * HF;
  } else {
    const int j = idx - 2048;                    // wf [4096][1024]: 32 kt x 8 nt
    const int l = j >> 8;
    const int tt = j & 255;
    kk0 = (tt >> 3) * 128; n0 = (tt & 7) * 128;
    N = H_; K = F_;
    src = wf + (size_t)l * HF;
    dst = WtF + (size_t)l * HF;
  }
  // ---- read phase: 16 wave-wide asyncs, each = 2 fp32 rows (1KB) ----
  const int w = tid >> 6, li = tid & 63;
  #pragma unroll
  for (int q = 0; q < 16; ++q) {
    const int r2 = 2 * (q * 4 + w);              // wave-uniform row pair base
    async_ld16(&t[r2 * 128],
               src + (size_t)(kk0 + r2 + (li >> 5)) * N + n0 + (li & 31) * 4);
  }
  __syncthreads();                               // vmcnt(0) drain: tile staged
  // ---- write phase: 8 passes x (16 n-rows, 16 k-chunks of 8) ----
  #pragma unroll
  for (int p = 0; p < 8; ++p) {
    const int n = p * 16 + (tid >> 4);
    const int k0 = (tid & 15) * 8;
    bf16x8 pk;
    #pragma unroll
    for (int j = 0; j < 8; ++j) pk[j] = (bf16)t[(k0 + j) * 128 + n];
    *(bf16x8*)(dst + (size_t)(n0 + n) * K + kk0 + k0) = pk;
  }
}

// ---------------- double-buffered GEMM core: C[128x128] = A[.][ld] @ Bt[.][ld]^T
__device__ __forceinline__ void gemm_core(
    const bf16* __restrict__ A, const bf16* __restrict__ Bt, int ld, int kLen,
    int m0, int n0, bf16* As, bf16* Bs, f32x4 (&acc)[4][4]) {
  const int tid = (int)threadIdx.x;
  const int w = tid >> 6, l = tid & 63;
  const int lr = l & 15, lg = l >> 4;
  const int wm = w >> 1, wn = w & 1;
  const int srow = l >> 2;
  const int scol = (l & 3) * 8;

  const bf16* ag = A  + (size_t)(m0 + w * 32 + srow) * ld + scol;
  const bf16* bg = Bt + (size_t)(n0 + w * 32 + srow) * ld + scol;
  const int soff = (w * 32) * 32;

  auto stage = [&](int buf, int kk) {
    bf16* ad = As + buf * 4096 + soff;
    bf16* bd = Bs + buf * 4096 + soff;
    async_ld16(ad,           ag + kk);
    async_ld16(ad + 16 * 32, ag + kk + (size_t)16 * ld);
    async_ld16(bd,           bg + kk);
    async_ld16(bd + 16 * 32, bg + kk + (size_t)16 * ld);
  };

  stage(0, 0);
  __syncthreads();
  int cur = 0;
  for (int k0 = 0; k0 < kLen; k0 += 32) {
    if (k0 + 32 < kLen) stage(cur ^ 1, k0 + 32);
    const bf16* Ab = As + cur * 4096;
    const bf16* Bb = Bs + cur * 4096;
    bf16x8 af[4], bv[4];
    #pragma unroll
    for (int i = 0; i < 4; ++i)
      af[i] = *(const bf16x8*)(Ab + (wm * 64 + i * 16 + lr) * 32 + lg * 8);
    #pragma unroll
    for (int i = 0; i < 4; ++i)
      bv[i] = *(const bf16x8*)(Bb + (wn * 64 + i * 16 + lr) * 32 + lg * 8);
    #pragma unroll
    for (int i = 0; i < 4; ++i)
      #pragma unroll
      for (int j = 0; j < 4; ++j)
        acc[i][j] = __builtin_amdgcn_mfma_f32_16x16x32_bf16(af[i], bv[j], acc[i][j], 0, 0, 0);
    __syncthreads();
    cur ^= 1;
  }
}

// MODE 1: out_bf16 = gelu(acc+bias) | MODE 3: bf16 partial -> outb[z*M*N + idx]
template <int MODE>
__global__ __launch_bounds__(256) void gemm128_kernel(
    const bf16* __restrict__ A, const bf16* __restrict__ Bt,
    const float* __restrict__ bias, bf16* __restrict__ outb,
    int N, int K, int kSlice) {
  __shared__ __align__(16) bf16 As[2 * 128 * 32];
  __shared__ __align__(16) bf16 Bs[2 * 128 * 32];
  const int m0 = blockIdx.y * 128, n0 = blockIdx.x * 128;
  const int z = blockIdx.z;
  const f32x4 z4 = {0.f, 0.f, 0.f, 0.f};
  f32x4 acc[4][4];
  #pragma unroll
  for (int i = 0; i < 4; ++i)
    #pragma unroll
    for (int j = 0; j < 4; ++j) acc[i][j] = z4;

  gemm_core(A + (size_t)z * kSlice, Bt + (size_t)z * kSlice, K, kSlice,
            m0, n0, As, Bs, acc);

  const int tid = (int)threadIdx.x;
  const int w = tid >> 6, l = tid & 63;
  const int lr = l & 15, lg = l >> 4;
  const int wm = w >> 1, wn = w & 1;
  const size_t pbase = (MODE == 3) ? (size_t)z * M_ * (size_t)N : 0;
  #pragma unroll
  for (int i = 0; i < 4; ++i) {
    const int row0 = m0 + wm * 64 + i * 16 + lg * 4;
    #pragma unroll
    for (int j = 0; j < 4; ++j) {
      const int col = n0 + wn * 64 + j * 16 + lr;
      const float bvx = (MODE == 3) ? 0.f : bias[col];
      #pragma unroll
      for (int r = 0; r < 4; ++r) {
        const size_t idx = (size_t)(row0 + r) * N + col;
        float v = acc[i][j][r] + bvx;
        if (MODE == 3) {
          outb[pbase + idx] = (bf16)v;
        } else {
          outb[idx] = (bf16)gelu_tanh(v);
        }
      }
    }
  }
}

// ---------------- split-K reduce (bf16 partials, z=4) + bias + ReZero ---------
__global__ __launch_bounds__(256) void reduce_residual(
    const bf16x4* __restrict__ part, const float* __restrict__ bias,
    const float* __restrict__ alphap, float4* __restrict__ xf,
    bf16x4* __restrict__ xb) {
  const int i = blockIdx.x * 256 + (int)threadIdx.x;   // over M_*H_/4
  const int nper = M_ * H_ / 4;
  float s[4] = {0.f, 0.f, 0.f, 0.f};
  #pragma unroll
  for (int zz = 0; zz < 4; ++zz) {
    const bf16x4 p = part[i + (size_t)zz * nper];
    #pragma unroll
    for (int k = 0; k < 4; ++k) s[k] += (float)p[k];
  }
  const int col = (i * 4) & (H_ - 1);
  const float4 b4 = *(const float4*)(bias + col);
  const float a = *alphap;
  float4 xv = xf[i];
  xv.x += a * (s[0] + b4.x);
  xv.y += a * (s[1] + b4.y);
  xv.z += a * (s[2] + b4.z);
  xv.w += a * (s[3] + b4.w);
  xf[i] = xv;
  bf16x4 bb;
  bb[0] = (bf16)xv.x; bb[1] = (bf16)xv.y; bb[2] = (bf16)xv.z; bb[3] = (bf16)xv.w;
  xb[i] = bb;
}

// ---------------- QKV GEMM, BN=64 tile: grid (48, 16) = 768 blocks ------------
__global__ __launch_bounds__(256) void gemm_qkv64(
    const bf16* __restrict__ A, const bf16* __restrict__ Wt,
    const float* __restrict__ bq, const float* __restrict__ bk,
    const float* __restrict__ bvv,
    bf16* __restrict__ qo, bf16* __restrict__ ko, bf16* __restrict__ vt) {
  __shared__ __align__(16) bf16 As[2 * 128 * 32];
  __shared__ __align__(16) bf16 Bs[2 * 64 * 32];
  const int tid = (int)threadIdx.x;
  const int w = tid >> 6, l = tid & 63;
  const int lr = l & 15, lg = l >> 4;
  const int wm = w >> 1, wn = w & 1;
  const int srow = l >> 2, scol = (l & 3) * 8;
  const int m0 = blockIdx.y * 128, n0 = blockIdx.x * 64;

  const bf16* ag = A  + (size_t)(m0 + w * 32 + srow) * H_ + scol;
  const bf16* bg = Wt + (size_t)(n0 + w * 16 + srow) * H_ + scol;
  const int aoff = (w * 32) * 32;
  const int boff = (w * 16) * 32;

  auto stage = [&](int buf, int kk) {
    bf16* ad = As + buf * 4096 + aoff;
    bf16* bd = Bs + buf * 2048 + boff;
    async_ld16(ad,           ag + kk);
    async_ld16(ad + 16 * 32, ag + kk + (size_t)16 * H_);
    async_ld16(bd,           bg + kk);
  };

  const f32x4 z4 = {0.f, 0.f, 0.f, 0.f};
  f32x4 acc[4][2];
  #pragma unroll
  for (int i = 0; i < 4; ++i)
    #pragma unroll
    for (int j = 0; j < 2; ++j) acc[i][j] = z4;

  stage(0, 0);
  __syncthreads();
  int cur = 0;
  for (int k0 = 0; k0 < H_; k0 += 32) {
    if (k0 + 32 < H_) stage(cur ^ 1, k0 + 32);
    const bf16* Ab = As + cur * 4096;
    const bf16* Bb = Bs + cur * 2048;
    bf16x8 af[4], bv[2];
    #pragma unroll
    for (int i = 0; i < 4; ++i)
      af[i] = *(const bf16x8*)(Ab + (wm * 64 + i * 16 + lr) * 32 + lg * 8);
    #pragma unroll
    for (int j = 0; j < 2; ++j)
      bv[j] = *(const bf16x8*)(Bb + (wn * 32 + j * 16 + lr) * 32 + lg * 8);
    #pragma unroll
    for (int i = 0; i < 4; ++i)
      #pragma unroll
      for (int j = 0; j < 2; ++j)
        acc[i][j] = __builtin_amdgcn_mfma_f32_16x16x32_bf16(af[i], bv[j], acc[i][j], 0, 0, 0);
    __syncthreads();
    cur ^= 1;
  }

  if (n0 < 2048) {  // Q or K: direct [B,S,H] store
    bf16* out = (n0 < 1024) ? qo : ko;
    const float* bias = (n0 < 1024) ? bq : bk;
    const int nl = n0 & 1023;
    #pragma unroll
    for (int i = 0; i < 4; ++i) {
      const int row0 = m0 + wm * 64 + i * 16 + lg * 4;
      #pragma unroll
      for (int j = 0; j < 2; ++j) {
        const int col = nl + wn * 32 + j * 16 + lr;
        const float bvx = bias[col];
        #pragma unroll
        for (int r = 0; r < 4; ++r)
          out[(size_t)(row0 + r) * H_ + col] = (bf16)(acc[i][j][r] + bvx);
      }
    }
  } else {          // V: transposed store Vt[((b*NH+h)*DH+d)*S + s]
    const int hh = (n0 >> 6) - 32;
    #pragma unroll
    for (int i = 0; i < 4; ++i) {
      const int row0 = m0 + wm * 64 + i * 16 + lg * 4;
      const int bb = row0 >> 10, ss = row0 & (S_ - 1);
      #pragma unroll
      for (int j = 0; j < 2; ++j) {
        const int dd = wn * 32 + j * 16 + lr;
        const float bvx = bvv[hh * 64 + dd];
        bf16x4 pk;
        #pragma unroll
        for (int r = 0; r < 4; ++r) pk[r] = (bf16)(acc[i][j][r] + bvx);
        *(bf16x4*)(vt + (((size_t)(bb * NH_ + hh) * DH_ + dd) << 10) + ss) = pk;
      }
    }
  }
}

// ---------------- flash attention v7: LDS-staged K/V + mask reg-pipeline ------
__global__ __launch_bounds__(256) void attn_kernel7(
    const bf16* __restrict__ Q, const bf16* __restrict__ Kb,
    const bf16* __restrict__ Vt, const bf16* __restrict__ madd,
    bf16* __restrict__ Ctx) {
  const int tid = (int)threadIdx.x;
  const int w = tid >> 6, l = tid & 63;
  const int lr = l & 15, lg = l >> 4;
  const int r7 = lr & 7;
  const int h = blockIdx.y, b = blockIdx.z;
  const int q0 = blockIdx.x * 64 + w * 16;

  __shared__ __align__(16) bf16 Kt[2][64 * 64];  // [buf][kv][d] swizzled
  __shared__ __align__(16) bf16 Vs[2][64 * 64];  // [buf][d][kv] swizzled
  __shared__ unsigned int Pu[4][16][36];         // per-wave P, u32-packed bf16

  const bf16* qp = Q + ((size_t)(b * S_ + q0 + lr)) * H_ + h * DH_;
  const bf16x8 qa0 = *(const bf16x8*)(qp + lg * 8);
  const bf16x8 qa1 = *(const bf16x8*)(qp + 32 + lg * 8);

  const f32x4 z4 = {0.f, 0.f, 0.f, 0.f};
  f32x4 acc[4];
  #pragma unroll
  for (int dt = 0; dt < 4; ++dt) acc[dt] = z4;
  float mrow = -1e30f, ssum = 0.f;

  const bf16* Kbase = Kb + ((size_t)b * S_) * H_ + h * DH_;
  const bf16* Vbase = Vt + ((size_t)(b * NH_ + h)) * DH_ * S_;
  const bf16* Mb = madd + ((size_t)(b * S_ + q0 + lr)) * S_;

  const float c1 = 0.125f * 1.44269504088896f;   // scale * log2(e)
  const float THR = 10.f;                        // defer-max headroom (base-2)

  const int sub = l >> 3;
  const int cs  = ((l & 7) ^ sub) * 8;
  auto stage = [&](int buf, int kv) {
    #pragma unroll
    for (int j = 0; j < 2; ++j) {
      const int rbase = w * 16 + j * 8;
      async_ld16(&Kt[buf][rbase * 64],
                 Kbase + (size_t)(kv + rbase + sub) * H_ + cs);
      async_ld16(&Vs[buf][rbase * 64],
                 Vbase + (size_t)(rbase + sub) * S_ + kv + cs);
    }
  };

  stage(0, 0);
  bf16x4 mk[4];
  #pragma unroll
  for (int t = 0; t < 4; ++t) mk[t] = *(const bf16x4*)(Mb + t * 16 + lg * 4);
  __syncthreads();                    // vmcnt(0) drain: tile 0 ready
  int cur = 0;
  #pragma unroll 1
  for (int it = 0; it < 16; ++it) {
    const int kv0 = it * 64;
    if (it < 15) stage(cur ^ 1, kv0 + 64);   // async prefetch next K/V tile
    bf16x4 mkn[4];
    if (it < 15) {
      #pragma unroll
      for (int t = 0; t < 4; ++t)
        mkn[t] = *(const bf16x4*)(Mb + kv0 + 64 + t * 16 + lg * 4);
    }
    const bf16* Kc = &Kt[cur][0];
    const bf16* Vc = &Vs[cur][0];
    bf16x8 kf0[4], kf1[4];
    #pragma unroll
    for (int t = 0; t < 4; ++t) {
      kf0[t] = *(const bf16x8*)(Kc + (t * 16 + lr) * 64 + ((lg ^ r7) * 8));
      kf1[t] = *(const bf16x8*)(Kc + (t * 16 + lr) * 64 + (((4 + lg) ^ r7) * 8));
    }
    f32x4 st[4];
    __builtin_amdgcn_s_setprio(1);
    #pragma unroll
    for (int t = 0; t < 4; ++t) {
      f32x4 s = __builtin_amdgcn_mfma_f32_16x16x32_bf16(kf0[t], qa0, z4, 0, 0, 0);
      st[t] = __builtin_amdgcn_mfma_f32_16x16x32_bf16(kf1[t], qa1, s, 0, 0, 0);
    }
    __builtin_amdgcn_s_setprio(0);
    float sv[4][4];
    #pragma unroll
    for (int t = 0; t < 4; ++t)
      #pragma unroll
      for (int r = 0; r < 4; ++r)
        sv[t][r] = st[t][r] * c1 + (float)mk[t][r];
    float nm = sv[0][0];
    #pragma unroll
    for (int t = 0; t < 4; ++t)
      #pragma unroll
      for (int r = 0; r < 4; ++r) nm = fmaxf(nm, sv[t][r]);
    nm = fmaxf(nm, __shfl_xor(nm, 16));
    nm = fmaxf(nm, __shfl_xor(nm, 32));
    if (__any(nm > mrow + THR)) {
      float newm = fmaxf(mrow, nm);
      float f = __builtin_amdgcn_exp2f(mrow - newm);
      mrow = newm;
      ssum *= f;
      #pragma unroll
      for (int dt = 0; dt < 4; ++dt)
        #pragma unroll
        for (int r = 0; r < 4; ++r) acc[dt][r] *= f;
    }
    float p[4][4];
    float ps = 0.f;
    #pragma unroll
    for (int t = 0; t < 4; ++t)
      #pragma unroll
      for (int r = 0; r < 4; ++r) {
        p[t][r] = __builtin_amdgcn_exp2f(sv[t][r] - mrow);
        ps += p[t][r];
      }
    ps += __shfl_xor(ps, 16);
    ps += __shfl_xor(ps, 32);
    ssum += ps;
    #pragma unroll
    for (int t = 0; t < 4; ++t)
      #pragma unroll
      for (int hh = 0; hh < 2; ++hh) {
        union { bf16x2 v; unsigned int u; } pk;
        pk.v[0] = (bf16)p[t][2 * hh];
        pk.v[1] = (bf16)p[t][2 * hh + 1];
        Pu[w][lr][8 * t + 2 * lg + hh] = pk.u;
      }
    const bf16x8 pf0 = *(const bf16x8*)&Pu[w][lr][4 * lg];
    const bf16x8 pf1 = *(const bf16x8*)&Pu[w][lr][16 + 4 * lg];
    __builtin_amdgcn_s_setprio(1);
    #pragma unroll
    for (int dt = 0; dt < 4; ++dt) {
      bf16x8 vb0 = *(const bf16x8*)(Vc + (dt * 16 + lr) * 64 + ((lg ^ r7) * 8));
      acc[dt] = __builtin_amdgcn_mfma_f32_16x16x32_bf16(vb0, pf0, acc[dt], 0, 0, 0);
    }
    #pragma unroll
    for (int dt = 0; dt < 4; ++dt) {
      bf16x8 vb1 = *(const bf16x8*)(Vc + (dt * 16 + lr) * 64 + (((4 + lg) ^ r7) * 8));
      acc[dt] = __builtin_amdgcn_mfma_f32_16x16x32_bf16(vb1, pf1, acc[dt], 0, 0, 0);
    }
    __builtin_amdgcn_s_setprio(0);
    if (it < 15) {
      #pragma unroll
      for (int t = 0; t < 4; ++t) mk[t] = mkn[t];
    }
    __syncthreads();                  // drains prefetch (next tile ready), frees cur
    cur ^= 1;
  }
  const float inv = 1.f / ssum;
  bf16* cp = Ctx + ((size_t)(b * S_ + q0 + lr)) * H_ + h * DH_;
  #pragma unroll
  for (int dt = 0; dt < 4; ++dt) {
    bf16x4 o;
    #pragma unroll
    for (int r = 0; r < 4; ++r) o[r] = (bf16)(acc[dt][r] * inv);
    *(bf16x4*)(cp + dt * 16 + lg * 4) = o;
  }
}

// ---------------- launcher ----------------------------------------------------
extern "C" void kernel_launch(void* const* d_in, const int* in_sizes, int n_in,
                              void* d_out, int out_size, void* d_ws, size_t ws_size,
                              hipStream_t stream) {
  (void)in_sizes; (void)n_in; (void)out_size; (void)ws_size;
  const float* x    = (const float*)d_in[0];
  const float* mask = (const float*)d_in[1];
  const float* wq   = (const float*)d_in[2];
  const float* bq   = (const float*)d_in[3];
  const float* wk   = (const float*)d_in[4];
  const float* bk   = (const float*)d_in[5];
  const float* wv   = (const float*)d_in[6];
  const float* bv   = (const float*)d_in[7];
  const float* wo   = (const float*)d_in[8];
  const float* bo   = (const float*)d_in[9];
  const float* aat  = (const float*)d_in[10];
  const float* wi   = (const float*)d_in[11];
  const float* bi   = (const float*)d_in[12];
  const float* wf   = (const float*)d_in[13];
  const float* bf_  = (const float*)d_in[14];
  const float* afn  = (const float*)d_in[15];

  char* ws = (char*)d_ws;
  size_t o = 0;
  bf16* WtQKV = (bf16*)(ws + o); o += (size_t)L_ * 3 * H_ * H_ * 2; // 24MB
  bf16* WtO = (bf16*)(ws + o); o += (size_t)L_ * H_ * H_ * 2;       //  8MB
  bf16* WtI = (bf16*)(ws + o); o += (size_t)L_ * H_ * F_ * 2;       // 32MB
  bf16* WtF = (bf16*)(ws + o); o += (size_t)L_ * F_ * H_ * 2;       // 32MB
  bf16* madd = (bf16*)(ws + o); o += (size_t)B_ * S_ * S_ * 2;      //  4MB
  bf16* xb  = (bf16*)(ws + o); o += (size_t)M_ * H_ * 2;            //  4MB
  bf16* qb  = (bf16*)(ws + o); o += (size_t)M_ * H_ * 2;
  bf16* kbf = (bf16*)(ws + o); o += (size_t)M_ * H_ * 2;
  bf16* vt  = (bf16*)(ws + o); o += (size_t)M_ * H_ * 2;
  bf16* ctx = (bf16*)(ws + o); o += (size_t)M_ * H_ * 2;
  bf16* itm = (bf16*)(ws + o); o += (size_t)M_ * F_ * 2;            // 16MB
  bf16* partb = (bf16*)(ws + o); o += (size_t)4 * M_ * H_ * 2;      // 16MB

  float* xf = (float*)d_out;  // running x lives in d_out (fp32)

  const size_t HH = (size_t)H_ * H_;
  prep_all<<<dim3(7168), 256, 0, stream>>>(
      wq, wk, wv, wo, wi, wf, WtQKV, WtO, WtI, WtF,
      (const float4*)mask, (bf16x4*)madd, (const float4*)x, (float4*)xf,
      (bf16x4*)xb);

  for (int l = 0; l < L_; ++l) {
    gemm_qkv64<<<dim3(48, M_/128), 256, 0, stream>>>(
        xb, WtQKV + (size_t)l * 3 * HH,
        bq + l * H_, bk + l * H_, bv + l * H_, qb, kbf, vt);
    attn_kernel7<<<dim3(S_/64, NH_, B_), 256, 0, stream>>>(
        qb, kbf, vt, madd, ctx);
    gemm128_kernel<3><<<dim3(H_/128, M_/128, 4), 256, 0, stream>>>(
        ctx, WtO + (size_t)l * HH, nullptr, partb, H_, H_, H_ / 4);
    reduce_residual<<<dim3((M_ * H_ / 4) / 256), 256, 0, stream>>>(
        (const bf16x4*)partb, bo + l * H_, aat + l, (float4*)xf, (bf16x4*)xb);
    gemm128_kernel<1><<<dim3(F_/128, M_/128), 256, 0, stream>>>(
        xb, WtI + (size_t)l * H_ * F_, bi + l * F_, itm, F_, H_, H_);
    gemm128_kernel<3><<<dim3(H_/128, M_/128, 4), 256, 0, stream>>>(
        itm, WtF + (size_t)l * F_ * H_, nullptr, partb, H_, F_, F_ / 4);
    reduce_residual<<<dim3((M_ * H_ / 4) / 256), 256, 0, stream>>>(
        (const bf16x4*)partb, bf_ + l * H_, afn + l, (float4*)xf, (bf16x4*)xb);
  }
}